// Round 1
// baseline (2376.058 us; speedup 1.0000x reference)
//
#include <hip/hip_runtime.h>

// Problem constants (from reference): N=50000, E=800000, IN=128, HID=64, OUT=40
#define HID 64
#define JK_DIM 192
#define OUT_DIM 40

// ---------------------------------------------------------------------------
// GEMM: out[n,64] = h[n,K] @ W[K,64].  W staged in LDS (K*64*4 bytes).
// One thread per output element: 4 rows x 64 cols per 256-thread block.
// ---------------------------------------------------------------------------
template <int K>
__global__ __launch_bounds__(256) void gemm_k(const float* __restrict__ h,
                                              const float* __restrict__ W,
                                              float* __restrict__ out, int n) {
    __shared__ float Wl[K * HID];
    for (int i = threadIdx.x; i < K * HID; i += 256) Wl[i] = W[i];
    __syncthreads();
    int row = blockIdx.x * 4 + (threadIdx.x >> 6);
    int col = threadIdx.x & 63;
    if (row >= n) return;
    const float* hr = h + (long)row * K;
    float s = 0.f;
#pragma unroll
    for (int k = 0; k < K; k += 4) {
        float4 hv = *(const float4*)(hr + k);
        s += hv.x * Wl[(k + 0) * HID + col];
        s += hv.y * Wl[(k + 1) * HID + col];
        s += hv.z * Wl[(k + 2) * HID + col];
        s += hv.w * Wl[(k + 3) * HID + col];
    }
    out[(long)row * HID + col] = s;
}

// ---------------------------------------------------------------------------
// Edge scatter: agg[dst[e],:] += lin[src[e],:] * ew[e]
// 16 threads per edge, each handles 4 contiguous columns (float4 gather,
// 4 scalar f32 atomicAdds).
// ---------------------------------------------------------------------------
__global__ __launch_bounds__(256) void scatter_edges(const float* __restrict__ lin,
                                                     const int* __restrict__ src,
                                                     const int* __restrict__ dst,
                                                     const float* __restrict__ ew,
                                                     float* __restrict__ agg, int E) {
    long idx = (long)blockIdx.x * 256 + threadIdx.x;
    int e = (int)(idx >> 4);
    if (e >= E) return;
    int c = (int)(idx & 15) << 2;
    int s = src[e];
    int d = dst[e];
    float w = ew[e];
    float4 v = *(const float4*)(lin + (long)s * HID + c);
    float* ap = agg + (long)d * HID + c;
    atomicAdd(ap + 0, v.x * w);
    atomicAdd(ap + 1, v.y * w);
    atomicAdd(ap + 2, v.z * w);
    atomicAdd(ap + 3, v.w * w);
}

// ---------------------------------------------------------------------------
// h = relu(agg + b)   elementwise over n*64
// ---------------------------------------------------------------------------
__global__ __launch_bounds__(256) void bias_relu(const float* __restrict__ agg,
                                                 const float* __restrict__ b,
                                                 float* __restrict__ h, int n64) {
    int i = blockIdx.x * 256 + threadIdx.x;
    if (i >= n64) return;
    float v = agg[i] + b[i & 63];
    h[i] = v > 0.f ? v : 0.f;
}

// ---------------------------------------------------------------------------
// Final: out[n,40] = [h1|h2|h3][n,192] @ Wlin[192,40] + blin
// Wlin (30 KB) in LDS. 4 rows per block, cols padded to 64 lanes (40 active).
// ---------------------------------------------------------------------------
__global__ __launch_bounds__(256) void final_gemm(const float* __restrict__ h1,
                                                  const float* __restrict__ h2,
                                                  const float* __restrict__ h3,
                                                  const float* __restrict__ W,
                                                  const float* __restrict__ b,
                                                  float* __restrict__ out, int n) {
    __shared__ float Wl[JK_DIM * OUT_DIM];  // 7680 floats = 30 KB
    for (int i = threadIdx.x; i < JK_DIM * OUT_DIM; i += 256) Wl[i] = W[i];
    __syncthreads();
    int row = blockIdx.x * 4 + (threadIdx.x >> 6);
    int col = threadIdx.x & 63;
    if (row >= n || col >= OUT_DIM) return;
    float s = b[col];
    const float* segs[3] = {h1 + (long)row * HID, h2 + (long)row * HID, h3 + (long)row * HID};
#pragma unroll
    for (int seg = 0; seg < 3; ++seg) {
        const float* hr = segs[seg];
        const float* Wseg = Wl + seg * HID * OUT_DIM;
#pragma unroll
        for (int k = 0; k < HID; k += 4) {
            float4 hv = *(const float4*)(hr + k);
            s += hv.x * Wseg[(k + 0) * OUT_DIM + col];
            s += hv.y * Wseg[(k + 1) * OUT_DIM + col];
            s += hv.z * Wseg[(k + 2) * OUT_DIM + col];
            s += hv.w * Wseg[(k + 3) * OUT_DIM + col];
        }
    }
    out[(long)row * OUT_DIM + col] = s;
}

// ---------------------------------------------------------------------------
extern "C" void kernel_launch(void* const* d_in, const int* in_sizes, int n_in,
                              void* d_out, int out_size, void* d_ws, size_t ws_size,
                              hipStream_t stream) {
    const float* x    = (const float*)d_in[0];
    const int*   ei   = (const int*)d_in[1];
    const float* ew   = (const float*)d_in[2];
    const float* W1   = (const float*)d_in[3];
    const float* b1   = (const float*)d_in[4];
    const float* W2   = (const float*)d_in[5];
    const float* b2   = (const float*)d_in[6];
    const float* W3   = (const float*)d_in[7];
    const float* b3   = (const float*)d_in[8];
    const float* Wlin = (const float*)d_in[9];
    const float* blin = (const float*)d_in[10];
    float* out = (float*)d_out;

    const int N = in_sizes[0] / 128;   // 50000
    const int E = in_sizes[2];         // 800000
    const int* src = ei;
    const int* dst = ei + E;

    // Workspace layout: lin | agg | h1 | h2 | h3   (each N*64 f32)
    float* ws  = (float*)d_ws;
    const long seg = (long)N * HID;
    float* lin = ws;
    float* agg = ws + seg;
    float* h1  = ws + 2 * seg;
    float* h2  = ws + 3 * seg;
    float* h3  = ws + 4 * seg;

    const int n64 = N * HID;
    dim3 blk(256);
    dim3 gGemm((N + 3) / 4);
    dim3 gScat((int)(((long)E * 16 + 255) / 256));
    dim3 gElem((n64 + 255) / 256);

    // ---- layer 1 (K=128) ----
    gemm_k<128><<<gGemm, blk, 0, stream>>>(x, W1, lin, N);
    hipMemsetAsync(agg, 0, seg * sizeof(float), stream);
    scatter_edges<<<gScat, blk, 0, stream>>>(lin, src, dst, ew, agg, E);
    bias_relu<<<gElem, blk, 0, stream>>>(agg, b1, h1, n64);

    // ---- layer 2 (K=64) ----
    gemm_k<64><<<gGemm, blk, 0, stream>>>(h1, W2, lin, N);
    hipMemsetAsync(agg, 0, seg * sizeof(float), stream);
    scatter_edges<<<gScat, blk, 0, stream>>>(lin, src, dst, ew, agg, E);
    bias_relu<<<gElem, blk, 0, stream>>>(agg, b2, h2, n64);

    // ---- layer 3 (K=64) ----
    gemm_k<64><<<gGemm, blk, 0, stream>>>(h2, W3, lin, N);
    hipMemsetAsync(agg, 0, seg * sizeof(float), stream);
    scatter_edges<<<gScat, blk, 0, stream>>>(lin, src, dst, ew, agg, E);
    bias_relu<<<gElem, blk, 0, stream>>>(agg, b3, h3, n64);

    // ---- JumpingKnowledge concat + linear ----
    final_gemm<<<gGemm, blk, 0, stream>>>(h1, h2, h3, Wlin, blin, out, N);
}

// Round 2
// 637.525 us; speedup vs baseline: 3.7270x; 3.7270x over previous
//
#include <hip/hip_runtime.h>

// Problem constants: N=50000, E=800000, IN=128, HID=64, OUT=40
#define HID 64
#define JK_DIM 192
#define OUT_DIM 40

// ---------------------------------------------------------------------------
// GEMM: out[n,64] = h[n,K] @ W[K,64].  W staged in LDS.
// ---------------------------------------------------------------------------
template <int K>
__global__ __launch_bounds__(256) void gemm_k(const float* __restrict__ h,
                                              const float* __restrict__ W,
                                              float* __restrict__ out, int n) {
    __shared__ float Wl[K * HID];
    for (int i = threadIdx.x; i < K * HID; i += 256) Wl[i] = W[i];
    __syncthreads();
    int row = blockIdx.x * 4 + (threadIdx.x >> 6);
    int col = threadIdx.x & 63;
    if (row >= n) return;
    const float* hr = h + (long)row * K;
    float s = 0.f;
#pragma unroll
    for (int k = 0; k < K; k += 4) {
        float4 hv = *(const float4*)(hr + k);
        s += hv.x * Wl[(k + 0) * HID + col];
        s += hv.y * Wl[(k + 1) * HID + col];
        s += hv.z * Wl[(k + 2) * HID + col];
        s += hv.w * Wl[(k + 3) * HID + col];
    }
    out[(long)row * HID + col] = s;
}

// ---------------------------------------------------------------------------
// CSR build: histogram of dst, exclusive scan, atomic-slot fill.
// ---------------------------------------------------------------------------
__global__ __launch_bounds__(256) void hist_dst(const int* __restrict__ dst,
                                                int* __restrict__ deg, int E) {
    int e = blockIdx.x * 256 + threadIdx.x;
    if (e < E) atomicAdd(&deg[dst[e]], 1);
}

// Pass A: per-block exclusive scan of deg -> off, block totals -> bsum
__global__ __launch_bounds__(256) void scan_a(const int* __restrict__ deg,
                                              int* __restrict__ off,
                                              int* __restrict__ bsum, int n) {
    __shared__ int tmp[256];
    int i = blockIdx.x * 256 + threadIdx.x;
    int v = (i < n) ? deg[i] : 0;
    tmp[threadIdx.x] = v;
    __syncthreads();
    for (int d = 1; d < 256; d <<= 1) {
        int t = (threadIdx.x >= d) ? tmp[threadIdx.x - d] : 0;
        __syncthreads();
        tmp[threadIdx.x] += t;
        __syncthreads();
    }
    if (i < n) off[i] = tmp[threadIdx.x] - v;
    if (threadIdx.x == 255) bsum[blockIdx.x] = tmp[255];
}

// Pass B: single-block exclusive scan of bsum (nblk <= 256)
__global__ __launch_bounds__(256) void scan_b(int* __restrict__ bsum, int nblk) {
    __shared__ int tmp[256];
    int v = (threadIdx.x < nblk) ? bsum[threadIdx.x] : 0;
    tmp[threadIdx.x] = v;
    __syncthreads();
    for (int d = 1; d < 256; d <<= 1) {
        int t = (threadIdx.x >= d) ? tmp[threadIdx.x - d] : 0;
        __syncthreads();
        tmp[threadIdx.x] += t;
        __syncthreads();
    }
    if (threadIdx.x < nblk) bsum[threadIdx.x] = tmp[threadIdx.x] - v;
}

// Pass C: add block offsets; replicate into pos (fill cursor)
__global__ __launch_bounds__(256) void scan_c(int* __restrict__ off,
                                              const int* __restrict__ bsum,
                                              int* __restrict__ pos, int n) {
    int i = blockIdx.x * 256 + threadIdx.x;
    if (i >= n) return;
    int o = off[i] + bsum[blockIdx.x];
    off[i] = o;
    pos[i] = o;
}

// Fill: edge (src, weight) packed 8B into dst-sorted order
__global__ __launch_bounds__(256) void fill_csr(const int* __restrict__ src,
                                                const int* __restrict__ dst,
                                                const float* __restrict__ ew,
                                                int* __restrict__ pos,
                                                int2* __restrict__ ecsr, int E) {
    int e = blockIdx.x * 256 + threadIdx.x;
    if (e >= E) return;
    int p = atomicAdd(&pos[dst[e]], 1);
    int2 v;
    v.x = src[e];
    v.y = __float_as_int(ew[e]);
    ecsr[p] = v;
}

// ---------------------------------------------------------------------------
// Aggregate + bias + ReLU: one wave per dst node, lane = column.
// h[node,c] = relu( sum_{e in seg(node)} lin[src_e, c]*w_e + b[c] )
// ---------------------------------------------------------------------------
__global__ __launch_bounds__(256) void aggregate(const float* __restrict__ lin,
                                                 const int2* __restrict__ ecsr,
                                                 const int* __restrict__ off,
                                                 const int* __restrict__ deg,
                                                 const float* __restrict__ bias,
                                                 float* __restrict__ h, int n) {
    int node = blockIdx.x * 4 + (threadIdx.x >> 6);
    int lane = threadIdx.x & 63;
    if (node >= n) return;
    int start = off[node];
    int cnt = deg[node];
    float acc = 0.f;
    for (int j = 0; j < cnt; ++j) {
        int2 ev = ecsr[start + j];
        float w = __int_as_float(ev.y);
        acc += lin[(long)ev.x * HID + lane] * w;
    }
    float v = acc + bias[lane];
    h[(long)node * HID + lane] = v > 0.f ? v : 0.f;
}

// ---------------------------------------------------------------------------
// Final: out[n,40] = [h1|h2|h3][n,192] @ Wlin[192,40] + blin
// ---------------------------------------------------------------------------
__global__ __launch_bounds__(256) void final_gemm(const float* __restrict__ h1,
                                                  const float* __restrict__ h2,
                                                  const float* __restrict__ h3,
                                                  const float* __restrict__ W,
                                                  const float* __restrict__ b,
                                                  float* __restrict__ out, int n) {
    __shared__ float Wl[JK_DIM * OUT_DIM];  // 30 KB
    for (int i = threadIdx.x; i < JK_DIM * OUT_DIM; i += 256) Wl[i] = W[i];
    __syncthreads();
    int row = blockIdx.x * 4 + (threadIdx.x >> 6);
    int col = threadIdx.x & 63;
    if (row >= n || col >= OUT_DIM) return;
    float s = b[col];
    const float* segs[3] = {h1 + (long)row * HID, h2 + (long)row * HID, h3 + (long)row * HID};
#pragma unroll
    for (int seg = 0; seg < 3; ++seg) {
        const float* hr = segs[seg];
        const float* Wseg = Wl + seg * HID * OUT_DIM;
#pragma unroll
        for (int k = 0; k < HID; k += 4) {
            float4 hv = *(const float4*)(hr + k);
            s += hv.x * Wseg[(k + 0) * OUT_DIM + col];
            s += hv.y * Wseg[(k + 1) * OUT_DIM + col];
            s += hv.z * Wseg[(k + 2) * OUT_DIM + col];
            s += hv.w * Wseg[(k + 3) * OUT_DIM + col];
        }
    }
    out[(long)row * OUT_DIM + col] = s;
}

// ---------------------------------------------------------------------------
extern "C" void kernel_launch(void* const* d_in, const int* in_sizes, int n_in,
                              void* d_out, int out_size, void* d_ws, size_t ws_size,
                              hipStream_t stream) {
    const float* x    = (const float*)d_in[0];
    const int*   ei   = (const int*)d_in[1];
    const float* ew   = (const float*)d_in[2];
    const float* W1   = (const float*)d_in[3];
    const float* b1   = (const float*)d_in[4];
    const float* W2   = (const float*)d_in[5];
    const float* b2   = (const float*)d_in[6];
    const float* W3   = (const float*)d_in[7];
    const float* b3   = (const float*)d_in[8];
    const float* Wlin = (const float*)d_in[9];
    const float* blin = (const float*)d_in[10];
    float* out = (float*)d_out;

    const int N = in_sizes[0] / 128;   // 50000
    const int E = in_sizes[2];         // 800000
    const int* src = ei;
    const int* dst = ei + E;

    // Workspace layout (bytes):
    //   lin, h1, h2, h3 : N*64 f32 each (51.2 MB total)
    //   deg, off, pos   : N i32 each
    //   bsum            : 256 i32
    //   ecsr            : E int2 (6.4 MB)
    char* wsb = (char*)d_ws;
    const long seg = (long)N * HID;
    float* lin = (float*)wsb;                       wsb += seg * 4;
    float* h1  = (float*)wsb;                       wsb += seg * 4;
    float* h2  = (float*)wsb;                       wsb += seg * 4;
    float* h3  = (float*)wsb;                       wsb += seg * 4;
    int* deg   = (int*)wsb;                         wsb += (long)N * 4;
    int* off   = (int*)wsb;                         wsb += (long)N * 4;
    int* pos   = (int*)wsb;                         wsb += (long)N * 4;
    int* bsum  = (int*)wsb;                         wsb += 256 * 4;
    int2* ecsr = (int2*)wsb;

    dim3 blk(256);
    const int nblkN = (N + 255) / 256;     // 196
    dim3 gN(nblkN);
    dim3 gE((E + 255) / 256);              // 3125
    dim3 gGemm((N + 3) / 4);               // 12500

    // ---- CSR build (once per launch) ----
    hipMemsetAsync(deg, 0, (long)N * 4, stream);
    hist_dst<<<gE, blk, 0, stream>>>(dst, deg, E);
    scan_a<<<gN, blk, 0, stream>>>(deg, off, bsum, N);
    scan_b<<<1, blk, 0, stream>>>(bsum, nblkN);
    scan_c<<<gN, blk, 0, stream>>>(off, bsum, pos, N);
    fill_csr<<<gE, blk, 0, stream>>>(src, dst, ew, pos, ecsr, E);

    // ---- layer 1 (K=128) ----
    gemm_k<128><<<gGemm, blk, 0, stream>>>(x, W1, lin, N);
    aggregate<<<gGemm, blk, 0, stream>>>(lin, ecsr, off, deg, b1, h1, N);

    // ---- layer 2 ----
    gemm_k<64><<<gGemm, blk, 0, stream>>>(h1, W2, lin, N);
    aggregate<<<gGemm, blk, 0, stream>>>(lin, ecsr, off, deg, b2, h2, N);

    // ---- layer 3 ----
    gemm_k<64><<<gGemm, blk, 0, stream>>>(h2, W3, lin, N);
    aggregate<<<gGemm, blk, 0, stream>>>(lin, ecsr, off, deg, b3, h3, N);

    // ---- JumpingKnowledge concat + linear ----
    final_gemm<<<gGemm, blk, 0, stream>>>(h1, h2, h3, Wlin, blin, out, N);
}